// Round 6
// baseline (106.317 us; speedup 1.0000x reference)
//
#include <hip/hip_runtime.h>
#include <math.h>

#define NN 256
#define LL 4096
#define DL 64
#define DC 128
#define KS 15
#define LOUT (LL - KS + 1)   // 4082
#define RSQRT_DC 0.08838834764831843f
#define INV_LOUT (1.0f / (float)LOUT)

// ws layout (float offsets):
#define WS_QC    0         // 60*128  QC[j,c] = (Wq . ctb_j)[c]
#define WS_KC    7680      // 60*128  KC[j,c] = (Wk . ctb_j)[c]
#define WS_G     15360     // 60*128  G [j,c] = (Wv . ctb_j)[c]
#define WS_Q0    23040     // 128     q0   = bq + Wq.conv_b
#define WS_BETA  23168     // 128     beta = bk + Wk.conv_b
#define WS_OUTB  23296     // 128     outb = bv + Wv.conv_b

// ---------------- K1: weight algebra, 61 independent blocks ----------------
// blocks 0..59 (j = v*15+k): ctb_j inline, then QC/KC/G rows.
// block 60: q0, beta, outb.
__global__ __launch_bounds__(128) void prepw_kernel(
    const float* __restrict__ emb, const float* __restrict__ conv_w,
    const float* __restrict__ conv_b,
    const float* __restrict__ Wq, const float* __restrict__ bq,
    const float* __restrict__ Wk, const float* __restrict__ bk,
    const float* __restrict__ Wv, const float* __restrict__ bv,
    float* __restrict__ ws) {
    const int j = blockIdx.x, c = threadIdx.x;
    __shared__ __align__(16) float vecL[DC];
    if (j < 60) {
        const int v = j / KS, k = j % KS;
        __shared__ float embL[DL];
        if (c < DL) embL[c] = emb[v * DL + c];
        __syncthreads();
        const float* wp = conv_w + (size_t)c * (DL * KS) + k;
        float s = 0.f;
#pragma unroll
        for (int i = 0; i < DL; ++i) s += embL[i] * wp[i * KS];
        vecL[c] = s;
        __syncthreads();
    } else {
        vecL[c] = conv_b[c];
        __syncthreads();
    }
    const float4* x4  = (const float4*)vecL;
    const float4* wq4 = (const float4*)(Wq + (size_t)c * DC);
    const float4* wk4 = (const float4*)(Wk + (size_t)c * DC);
    const float4* wv4 = (const float4*)(Wv + (size_t)c * DC);
    float aq = 0.f, ak = 0.f, av = 0.f;
#pragma unroll 8
    for (int t = 0; t < 32; ++t) {
        const float4 x = x4[t], a = wq4[t], b = wk4[t], g = wv4[t];
        aq += a.x * x.x + a.y * x.y + a.z * x.z + a.w * x.w;
        ak += b.x * x.x + b.y * x.y + b.z * x.z + b.w * x.w;
        av += g.x * x.x + g.y * x.y + g.z * x.z + g.w * x.w;
    }
    if (j < 60) {
        ws[WS_QC + j * DC + c] = aq;
        ws[WS_KC + j * DC + c] = ak;
        ws[WS_G  + j * DC + c] = av;
    } else {
        ws[WS_Q0   + c] = aq + bq[c];
        ws[WS_BETA + c] = ak + bk[c];
        ws[WS_OUTB + c] = av + bv[c];
    }
}

template <int NW>
__device__ __forceinline__ float bsum(float v, float* red, int tid) {
#pragma unroll
    for (int off = 32; off > 0; off >>= 1) v += __shfl_down(v, off, 64);
    if ((tid & 63) == 0) red[tid >> 6] = v;
    __syncthreads();
    float r = 0.f;
#pragma unroll
    for (int w = 0; w < NW; ++w) r += red[w];
    __syncthreads();
    return r;
}

// ---------------- K2: per-sequence encode (self-packing) ----------------
__global__ __launch_bounds__(512) void encode_kernel(
    const int* __restrict__ tokens, const float* __restrict__ ws,
    float* __restrict__ out) {
    const int n = blockIdx.x, tid = threadIdx.x;

    __shared__ unsigned tok2L[258];
    __shared__ __align__(16) float qL[DC];
    __shared__ float stabL[64];     // [60] = base
    __shared__ float cfL[60];
    __shared__ float Tt[1024];
    __shared__ float AccL[45];
    __shared__ float red[8];
    __shared__ int totw[4][4];

    // ---- pack 16 tokens/dword + per-wave value counts (waves 0-3) ----
    if (tid < 256) {
        const int4* tv = (const int4*)(tokens + (size_t)n * LL) + tid * 4;
        unsigned w = 0;
#pragma unroll
        for (int m = 0; m < 4; ++m) {
            const int4 t4 = tv[m];
            w |= ((unsigned)t4.x | ((unsigned)t4.y << 2) |
                  ((unsigned)t4.z << 4) | ((unsigned)t4.w << 6)) << (8 * m);
        }
        tok2L[tid] = w;
        int c0, c1, c2, c3;
        unsigned y, z;
        y = w;               z = (y | (y >> 1)) & 0x55555555u; c0 = 16 - __popc(z);
        y = w ^ 0x55555555u; z = (y | (y >> 1)) & 0x55555555u; c1 = 16 - __popc(z);
        y = w ^ 0xAAAAAAAAu; z = (y | (y >> 1)) & 0x55555555u; c2 = 16 - __popc(z);
        y = w ^ 0xFFFFFFFFu; z = (y | (y >> 1)) & 0x55555555u; c3 = 16 - __popc(z);
#pragma unroll
        for (int off = 32; off > 0; off >>= 1) {
            c0 += __shfl_down(c0, off, 64); c1 += __shfl_down(c1, off, 64);
            c2 += __shfl_down(c2, off, 64); c3 += __shfl_down(c3, off, 64);
        }
        if ((tid & 63) == 0) {
            const int wv = tid >> 6;
            totw[wv][0] = c0; totw[wv][1] = c1; totw[wv][2] = c2; totw[wv][3] = c3;
        }
    } else {
        if (tid < 258) tok2L[tid] = 0u;
        const int i = tid - 258;
        if (i >= 0 && i < 45) AccL[i] = 0.f;
    }
    __syncthreads();

    // ---- wave0: cf -> q -> stab/base, wave-synchronous ----
    if (tid < 64) {
        const int l = tid;
        if (l < KS) {
            const int k = l;
            const unsigned dwF = tok2L[0], dwL = tok2L[255];
            const unsigned pm = (k == 0) ? 0u : ((1u << (2 * k)) - 1u);
            const unsigned sm = (k == 14) ? 0u : (0xFFFFFFFFu << (2 * (k + 2)));
            const int tot4[4] = {
                totw[0][0] + totw[1][0] + totw[2][0] + totw[3][0],
                totw[0][1] + totw[1][1] + totw[2][1] + totw[3][1],
                totw[0][2] + totw[1][2] + totw[2][2] + totw[3][2],
                totw[0][3] + totw[1][3] + totw[2][3] + totw[3][3]};
#pragma unroll
            for (int v = 0; v < 4; ++v) {
                const unsigned patt = (unsigned)v * 0x55555555u;
                unsigned yf = dwF ^ patt, zf = (yf | (yf >> 1)) & 0x55555555u;
                unsigned yl = dwL ^ patt, zl = (yl | (yl >> 1)) & 0x55555555u;
                const int pre = k - __popc(zf & pm);
                const int suf = (14 - k) - __popc(zl & sm);
                cfL[v * KS + k] = (float)(tot4[v] - pre - suf) * INV_LOUT;
            }
        }
        // q[c] = q0[c] + sum_j cf_j * QC[j,c]   (2 cols/lane)
        const int c0 = 2 * l;
        const float2 q02 = *(const float2*)(ws + WS_Q0 + c0);
        float u0 = q02.x, u1 = q02.y;
#pragma unroll 15
        for (int j = 0; j < 60; ++j) {
            const float cfj = cfL[j];
            const float2 q2 = *(const float2*)(ws + WS_QC + j * DC + c0);
            u0 += cfj * q2.x; u1 += cfj * q2.y;
        }
        qL[c0] = u0; qL[c0 + 1] = u1;
        // base = (q . beta) / sqrt(DC)
        const float2 be = *(const float2*)(ws + WS_BETA + c0);
        float t = u0 * be.x + u1 * be.y;
#pragma unroll
        for (int off = 32; off > 0; off >>= 1) t += __shfl_down(t, off, 64);
        if (l == 0) stabL[60] = t * RSQRT_DC;
        // stab[j] = (q . KC[j]) / sqrt(DC)
        if (l < 60) {
            const float4* kr = (const float4*)(ws + WS_KC + (size_t)l * DC);
            const float4* q4 = (const float4*)qL;
            float s = 0.f;
#pragma unroll 8
            for (int t2 = 0; t2 < 32; ++t2) {
                const float4 a = kr[t2], q = q4[t2];
                s += a.x * q.x + a.y * q.y + a.z * q.z + a.w * q.w;
            }
            stabL[l] = s * RSQRT_DC;
        }
    }
    __syncthreads();

    // ---- chunk tables: Tt[j*256+b] = sum_m stab[tok_m(b)*15 + 4j+m] ----
    const float base = stabL[60];
    for (int e = tid; e < 1024; e += 512) {
        const int j = e >> 8, bb = e & 255;
        float s = stabL[(bb & 3) * KS + 4 * j] +
                  stabL[((bb >> 2) & 3) * KS + 4 * j + 1] +
                  stabL[((bb >> 4) & 3) * KS + 4 * j + 2];
        if (j < 3) s += stabL[((bb >> 6) & 3) * KS + 4 * j + 3];
        Tt[e] = s;
    }
    // analytic upper bound on scores (softmax is shift-invariant)
    float M = base;
#pragma unroll
    for (int k = 0; k < KS; ++k)
        M += fmaxf(fmaxf(stabL[k], stabL[KS + k]),
                   fmaxf(stabL[2 * KS + k], stabL[3 * KS + k]));
    __syncthreads();

    // ---- scores -> e-values (registers only) ----
    const unsigned d0 = tok2L[tid >> 1], d1 = tok2L[(tid >> 1) + 1];
    const unsigned long long W = (unsigned long long)d0 | ((unsigned long long)d1 << 32);
    const int sbase = (tid & 1) << 4;
    const int t0 = tid * 8;
    float ev[8];
    float lsum = 0.f;
#pragma unroll
    for (int p = 0; p < 8; ++p) {
        const unsigned w = (unsigned)(W >> (sbase + 2 * p));
        const float s = base + Tt[w & 255] + Tt[256 + ((w >> 8) & 255)] +
                        Tt[512 + ((w >> 16) & 255)] + Tt[768 + ((w >> 24) & 63)];
        const float e = (t0 + p < LOUT) ? __expf(s - M) : 0.f;
        ev[p] = e; lsum += e;
    }
    const float S = bsum<8>(lsum, red, tid);
    const float invS = 1.0f / S;

    // ---- attn-weighted histogram (v=0 recovered from S) ----
    float a1[KS], a2[KS], a3[KS];
#pragma unroll
    for (int k = 0; k < KS; ++k) { a1[k] = 0.f; a2[k] = 0.f; a3[k] = 0.f; }
#pragma unroll
    for (int p = 0; p < 8; ++p) {
        const float e = ev[p];
        const unsigned w = (unsigned)(W >> (sbase + 2 * p));
#pragma unroll
        for (int k = 0; k < KS; ++k) {
            const int v = (int)((w >> (2 * k)) & 3u);
            a1[k] += (v == 1) ? e : 0.f;
            a2[k] += (v == 2) ? e : 0.f;
            a3[k] += (v == 3) ? e : 0.f;
        }
    }
    {
        const int lane = tid & 63;
#pragma unroll
        for (int k = 0; k < KS; ++k) {
            float v1 = a1[k], v2 = a2[k], v3 = a3[k];
#pragma unroll
            for (int off = 32; off > 0; off >>= 1) {
                v1 += __shfl_down(v1, off, 64);
                v2 += __shfl_down(v2, off, 64);
                v3 += __shfl_down(v3, off, 64);
            }
            if (lane == 0) {
                atomicAdd(&AccL[k], v1);
                atomicAdd(&AccL[KS + k], v2);
                atomicAdd(&AccL[2 * KS + k], v3);
            }
        }
    }
    __syncthreads();

    // ---- out[d] = outb[d] + invS * sum_j A_j * G[j,d] ----
    if (tid < DC) {
        float s = 0.f;
#pragma unroll
        for (int k = 0; k < KS; ++k) {
            const float a0 = S - AccL[k] - AccL[KS + k] - AccL[2 * KS + k];
            s += a0 * ws[WS_G + k * DC + tid];
        }
#pragma unroll
        for (int j = KS; j < 60; ++j) s += AccL[j - KS] * ws[WS_G + j * DC + tid];
        out[(size_t)n * DC + tid] = ws[WS_OUTB + tid] + s * invS;
    }
}

extern "C" void kernel_launch(void* const* d_in, const int* in_sizes, int n_in,
                              void* d_out, int out_size, void* d_ws, size_t ws_size,
                              hipStream_t stream) {
    const int*   tokens = (const int*)d_in[0];
    const float* emb    = (const float*)d_in[1];
    const float* conv_w = (const float*)d_in[2];
    const float* conv_b = (const float*)d_in[3];
    const float* Wq     = (const float*)d_in[4];
    const float* bq     = (const float*)d_in[5];
    const float* Wk     = (const float*)d_in[6];
    const float* bk     = (const float*)d_in[7];
    const float* Wv     = (const float*)d_in[8];
    const float* bv     = (const float*)d_in[9];
    float* out = (float*)d_out;
    float* ws  = (float*)d_ws;   // ~94 KB used

    prepw_kernel<<<61, 128, 0, stream>>>(emb, conv_w, conv_b,
                                         Wq, bq, Wk, bk, Wv, bv, ws);
    encode_kernel<<<NN, 512, 0, stream>>>(tokens, ws, out);
}